// Round 6
// baseline (328.326 us; speedup 1.0000x reference)
//
#include <hip/hip_runtime.h>

#define NSND   49152
#define NRECV  115200
#define NSROWS (2 * NSND)     // 98304 dense sender rows (both batches)
#define NRROWS (2 * NRECV)    // 230400 receiver rows

typedef __bf16 bx8 __attribute__((ext_vector_type(8)));
typedef float  fx4 __attribute__((ext_vector_type(4)));

__device__ __forceinline__ unsigned short f2bf(float f) {
  unsigned u = __float_as_uint(f);
  u += 0x7FFFu + ((u >> 16) & 1u);   // round-to-nearest-even
  return (unsigned short)(u >> 16);
}

// ---------- prep 1: c1[n] = b1f[n] + sum_i ef_sum[i] * w1f[256+i][n] ----------
__global__ void prep_c1(const float* __restrict__ w1e, const float* __restrict__ b1e,
                        const float* __restrict__ w2e, const float* __restrict__ b2e,
                        const float* __restrict__ w1f, const float* __restrict__ b1f,
                        float* __restrict__ c1) {
  __shared__ float s_sum[64];
  __shared__ float s_ef[64];
  int t = threadIdx.x;
  if (t < 64) {
    float w = w1e[t], b = b1e[t];
    float acc = 0.f;
    for (int k = 0; k < 4; ++k) {
      float v = (float)k * w + b;
      acc += v / (1.f + expf(-v));      // silu over the 4 edge-attr values
    }
    s_sum[t] = acc;
  }
  __syncthreads();
  if (t < 64) {
    float acc = 4.f * b2e[t];
    for (int j = 0; j < 64; ++j) acc += s_sum[j] * w2e[j * 64 + t];
    s_ef[t] = acc;
  }
  __syncthreads();
  if (t < 256) {
    float acc = b1f[t];
    for (int i = 0; i < 64; ++i) acc += s_ef[i] * w1f[(256 + i) * 256 + t];
    c1[t] = acc;
  }
}

// ---------- prep 2: weights -> bf16, MFMA-fragment-contiguous layout ----------
// frag[ct(16)][ks(8)][lane(64)][8 bf16]; element = W[k][n], n=ct*16+(lane&15),
// k = ks*32 + (lane>>4)*8 + j.  NOTE: because A- and B-fragment lane layouts are
// symmetric, this same buffer serves as the A-operand of W^T in the transposed
// GEMM (out^T = W^T @ X^T).
__global__ void prep_w(const float* __restrict__ w1f, const float* __restrict__ w2f,
                       unsigned short* __restrict__ W1f, unsigned short* __restrict__ W2f) {
  int idx  = blockIdx.x * blockDim.x + threadIdx.x;   // 0..8191
  int lane = idx & 63;
  int ks   = (idx >> 6) & 7;
  int ct   = idx >> 9;
  int n     = ct * 16 + (lane & 15);
  int kbase = ks * 32 + (lane >> 4) * 8;
  unsigned p1[4], p2[4];
#pragma unroll
  for (int h = 0; h < 4; ++h) {
    int k = kbase + 2 * h;
    p1[h] = (unsigned)f2bf(w1f[k * 256 + n]) | ((unsigned)f2bf(w1f[(k + 1) * 256 + n]) << 16);
    p2[h] = (unsigned)f2bf(w2f[k * 256 + n]) | ((unsigned)f2bf(w2f[(k + 1) * 256 + n]) << 16);
  }
  *(uint4*)(W1f + (size_t)idx * 8) = make_uint4(p1[0], p1[1], p1[2], p1[3]);
  *(uint4*)(W2f + (size_t)idx * 8) = make_uint4(p2[0], p2[1], p2[2], p2[3]);
}

// ---------- K1: Y' = x @ W1 + c1/4  (dense, 98304 sender rows, bf16 out) ----------
// grid 1536, block 256 (4 waves), 16 rows/wave, zero barriers.
// Transposed MFMA: acc[nc] = mfma(W1frag, Xfrag, acc) gives lane = (row=l&15,
// cols nc*16+(l>>4)*4..+3) -> direct packed uint2 store, no LDS repack.
__global__ __launch_bounds__(256, 4) void k1_senders(
    const float* __restrict__ x, const float* __restrict__ c1,
    const unsigned short* __restrict__ W1f, unsigned short* __restrict__ Yp) {
  __shared__ char lds[64 * 512];   // 32 KiB

  const int lane = threadIdx.x & 63;
  const int wv   = threadIdx.x >> 6;
  const int rb   = blockIdx.x * 64;           // global row base of block

  // stage 16 x-rows -> bf16 LDS (swizzled)
#pragma unroll 4
  for (int i = 0; i < 16; ++i) {
    int row = wv * 16 + i;
    const fx4* q = (const fx4*)(x + (size_t)(rb + row) * 256) + lane;
    fx4 a = __builtin_nontemporal_load(q);
    unsigned lo = (unsigned)f2bf(a.x) | ((unsigned)f2bf(a.y) << 16);
    unsigned hi = (unsigned)f2bf(a.z) | ((unsigned)f2bf(a.w) << 16);
    unsigned byte = (unsigned)(row * 512 + lane * 8) ^ (unsigned)((row & 7) << 4);
    *(uint2*)(lds + byte) = make_uint2(lo, hi);
  }

  fx4 acc[16];
#pragma unroll
  for (int nc = 0; nc < 16; ++nc) acc[nc] = (fx4){0.f, 0.f, 0.f, 0.f};

  const bx8* W1v = (const bx8*)W1f;
  const int arow = wv * 16 + (lane & 15);
  const unsigned aswz = (unsigned)((arow & 7) << 4);
  const unsigned alin = (unsigned)(arow * 512 + (lane >> 4) * 16);
#pragma unroll
  for (int ks = 0; ks < 8; ++ks) {
    bx8 xfr = *(const bx8*)(lds + ((alin + ks * 64) ^ aswz));
#pragma unroll
    for (int nc = 0; nc < 16; ++nc) {
      bx8 wfr = W1v[(nc * 8 + ks) * 64 + lane];
      acc[nc] = __builtin_amdgcn_mfma_f32_16x16x32_bf16(wfr, xfr, acc[nc], 0, 0, 0);
    }
  }

  // epilogue: Y'[row][col..col+3] = acc + c1/4, packed bf16 uint2 store
  const fx4* c1_4 = (const fx4*)c1;
  unsigned short* yrow = Yp + (size_t)(rb + wv * 16 + (lane & 15)) * 256;
#pragma unroll
  for (int nc = 0; nc < 16; ++nc) {
    fx4 c1v = c1_4[nc * 4 + (lane >> 4)];
    float v0 = acc[nc][0] + 0.25f * c1v.x;
    float v1 = acc[nc][1] + 0.25f * c1v.y;
    float v2 = acc[nc][2] + 0.25f * c1v.z;
    float v3 = acc[nc][3] + 0.25f * c1v.w;
    unsigned lo = (unsigned)f2bf(v0) | ((unsigned)f2bf(v1) << 16);
    unsigned hi = (unsigned)f2bf(v2) | ((unsigned)f2bf(v3) << 16);
    *(uint2*)(yrow + nc * 16 + (lane >> 4) * 4) = make_uint2(lo, hi);
  }
}

// ---------- K23: gather-sum Y' -> silu -> GEMM2 -> out ----------
// grid 3600, block 256 (4 waves), 16 receiver rows/wave, zero barriers.
// Index prefetch + grouped gather loads (16 loads in flight per lane).
// Transposed MFMA -> float4 nt output stores.
__global__ __launch_bounds__(256, 4) void k23_recv(
    const unsigned short* __restrict__ Yp, const int* __restrict__ edge_src,
    const unsigned short* __restrict__ W2f, const float* __restrict__ b2f,
    float* __restrict__ out) {
  __shared__ char lds[64 * 512];   // 32 KiB

  const int lane = threadIdx.x & 63;
  const int wv   = threadIdx.x >> 6;

  const int blk = blockIdx.x;
  const int b   = blk / 1800;                  // batch
  const int rr0 = (blk % 1800) * 64;           // receiver row base within batch
  const unsigned short* yb = Yp + (size_t)b * NSND * 256;
  const int4* esrc4 = (const int4*)edge_src;

  // prefetch ALL indices for this wave's 16 rows (one int4 per iteration slot)
  int4 sidx[8];
#pragma unroll
  for (int t = 0; t < 8; ++t)
    sidx[t] = esrc4[rr0 + wv * 16 + 2 * t + (lane >> 5)];

  const int chunk = lane & 31;                 // 16B chunk within 512B row
  // gather in 2 groups of 4 slots: issue 16 loads, then process
#pragma unroll
  for (int g = 0; g < 2; ++g) {
    bx8 d[4][4];
#pragma unroll
    for (int t = 0; t < 4; ++t) {
      int4 s = sidx[g * 4 + t];
      d[t][0] = *(const bx8*)(yb + (size_t)s.x * 256 + chunk * 8);
      d[t][1] = *(const bx8*)(yb + (size_t)s.y * 256 + chunk * 8);
      d[t][2] = *(const bx8*)(yb + (size_t)s.z * 256 + chunk * 8);
      d[t][3] = *(const bx8*)(yb + (size_t)s.w * 256 + chunk * 8);
    }
#pragma unroll
    for (int t = 0; t < 4; ++t) {
      int tt = g * 4 + t;
      int row = wv * 16 + 2 * tt + (lane >> 5);
      unsigned p[4];
#pragma unroll
      for (int h = 0; h < 4; ++h) {
        float v0 = (float)d[t][0][2*h] + (float)d[t][1][2*h] + (float)d[t][2][2*h] + (float)d[t][3][2*h];
        float v1 = (float)d[t][0][2*h+1] + (float)d[t][1][2*h+1] + (float)d[t][2][2*h+1] + (float)d[t][3][2*h+1];
        float h0 = v0 / (1.f + __expf(-v0));   // silu
        float h1 = v1 / (1.f + __expf(-v1));
        p[h] = (unsigned)f2bf(h0) | ((unsigned)f2bf(h1) << 16);
      }
      unsigned byte = (unsigned)(row * 512 + chunk * 16) ^ (unsigned)((row & 7) << 4);
      *(uint4*)(lds + byte) = make_uint4(p[0], p[1], p[2], p[3]);
    }
  }

  fx4 acc[16];
#pragma unroll
  for (int nc = 0; nc < 16; ++nc) acc[nc] = (fx4){0.f, 0.f, 0.f, 0.f};

  // GEMM2 (transposed): out^T tile = W2^T @ H^T -> mfma(Wfrag, Hfrag, acc)
  const bx8* W2v = (const bx8*)W2f;
  const int arow = wv * 16 + (lane & 15);
  const unsigned aswz = (unsigned)((arow & 7) << 4);
  const unsigned alin = (unsigned)(arow * 512 + (lane >> 4) * 16);
#pragma unroll
  for (int ks = 0; ks < 8; ++ks) {
    bx8 hfr = *(const bx8*)(lds + ((alin + ks * 64) ^ aswz));
#pragma unroll
    for (int nc = 0; nc < 16; ++nc) {
      bx8 wfr = W2v[(nc * 8 + ks) * 64 + lane];
      acc[nc] = __builtin_amdgcn_mfma_f32_16x16x32_bf16(wfr, hfr, acc[nc], 0, 0, 0);
    }
  }

  // epilogue: out[row][col..col+3] = acc + b2f, one nt float4 store per tile
  const fx4* b2f4 = (const fx4*)b2f;
  float* orow = out + ((size_t)b * NRECV + rr0 + wv * 16 + (lane & 15)) * 256;
#pragma unroll
  for (int nc = 0; nc < 16; ++nc) {
    fx4 bias = b2f4[nc * 4 + (lane >> 4)];
    fx4 o = acc[nc] + bias;
    __builtin_nontemporal_store(o, (fx4*)(orow + nc * 16 + (lane >> 4) * 4));
  }
}

// ---------- fallback (R3-validated fused kernel) if ws is too small ----------
__global__ __launch_bounds__(256, 4) void heal_fused(
    const float* __restrict__ x, const int* __restrict__ edge_src,
    const float* __restrict__ c1, const unsigned short* __restrict__ W1f,
    const unsigned short* __restrict__ W2f, const float* __restrict__ b2f,
    float* __restrict__ out) {
  __shared__ char lds[64 * 512];
  const int lane = threadIdx.x & 63;
  const int wv   = threadIdx.x >> 6;
  const int blk = blockIdx.x;
  const int b   = blk / 1800;
  const int r0  = (blk % 1800) * 64;
  const float* xb = x + (size_t)b * NSND * 256;
#pragma unroll 4
  for (int i = 0; i < 16; ++i) {
    int row = wv * 16 + i;
    int r   = r0 + row;
    int4 s  = *(const int4*)(edge_src + 4 * (size_t)r);
    float4 a0 = *((const float4*)(xb + (size_t)s.x * 256) + lane);
    float4 a1 = *((const float4*)(xb + (size_t)s.y * 256) + lane);
    float4 a2 = *((const float4*)(xb + (size_t)s.z * 256) + lane);
    float4 a3 = *((const float4*)(xb + (size_t)s.w * 256) + lane);
    float v0 = a0.x + a1.x + a2.x + a3.x;
    float v1 = a0.y + a1.y + a2.y + a3.y;
    float v2 = a0.z + a1.z + a2.z + a3.z;
    float v3 = a0.w + a1.w + a2.w + a3.w;
    unsigned lo = (unsigned)f2bf(v0) | ((unsigned)f2bf(v1) << 16);
    unsigned hi = (unsigned)f2bf(v2) | ((unsigned)f2bf(v3) << 16);
    unsigned byte = (unsigned)(row * 512 + lane * 8) ^ (unsigned)((row & 7) << 4);
    *(uint2*)(lds + byte) = make_uint2(lo, hi);
  }
  fx4 acc[16];
#pragma unroll
  for (int nc = 0; nc < 16; ++nc) acc[nc] = (fx4){0.f, 0.f, 0.f, 0.f};
  const bx8* W1v = (const bx8*)W1f;
  const int arow = wv * 16 + (lane & 15);
  const unsigned aswz = (unsigned)((arow & 7) << 4);
  const unsigned alin = (unsigned)(arow * 512 + (lane >> 4) * 16);
#pragma unroll
  for (int ks = 0; ks < 8; ++ks) {
    bx8 afr = *(const bx8*)(lds + ((alin + ks * 64) ^ aswz));
#pragma unroll
    for (int nc = 0; nc < 16; ++nc) {
      bx8 bfr = W1v[(nc * 8 + ks) * 64 + lane];
      acc[nc] = __builtin_amdgcn_mfma_f32_16x16x32_bf16(afr, bfr, acc[nc], 0, 0, 0);
    }
  }
  float c1v[16];
#pragma unroll
  for (int nc = 0; nc < 16; ++nc) c1v[nc] = c1[nc * 16 + (lane & 15)];
#pragma unroll
  for (int nc = 0; nc < 16; ++nc) {
    int hcol = nc * 16 + (lane & 15);
#pragma unroll
    for (int j = 0; j < 4; ++j) {
      float v = acc[nc][j] + c1v[nc];
      float h = v / (1.f + __expf(-v));
      int hrow = wv * 16 + (lane >> 4) * 4 + j;
      unsigned hb = (unsigned)(hrow * 512 + hcol * 2) ^ (unsigned)((hrow & 7) << 4);
      *(unsigned short*)(lds + hb) = f2bf(h);
    }
  }
#pragma unroll
  for (int nc = 0; nc < 16; ++nc) acc[nc] = (fx4){0.f, 0.f, 0.f, 0.f};
  const bx8* W2v = (const bx8*)W2f;
#pragma unroll
  for (int ks = 0; ks < 8; ++ks) {
    bx8 afr = *(const bx8*)(lds + ((alin + ks * 64) ^ aswz));
#pragma unroll
    for (int nc = 0; nc < 16; ++nc) {
      bx8 bfr = W2v[(nc * 8 + ks) * 64 + lane];
      acc[nc] = __builtin_amdgcn_mfma_f32_16x16x32_bf16(afr, bfr, acc[nc], 0, 0, 0);
    }
  }
  size_t obase = ((size_t)b * NRECV + r0) * 256;
#pragma unroll
  for (int nc = 0; nc < 16; ++nc) {
    int col = nc * 16 + (lane & 15);
    float bias = b2f[col];
#pragma unroll
    for (int j = 0; j < 4; ++j) {
      int row = wv * 16 + (lane >> 4) * 4 + j;
      out[obase + (size_t)row * 256 + col] = acc[nc][j] + bias;
    }
  }
}

extern "C" void kernel_launch(void* const* d_in, const int* in_sizes, int n_in,
                              void* d_out, int out_size, void* d_ws, size_t ws_size,
                              hipStream_t stream) {
  const float* x    = (const float*)d_in[0];
  const float* w1e  = (const float*)d_in[2];
  const float* b1e  = (const float*)d_in[3];
  const float* w2e  = (const float*)d_in[4];
  const float* b2e  = (const float*)d_in[5];
  const float* w1f  = (const float*)d_in[6];
  const float* b1f  = (const float*)d_in[7];
  const float* w2f  = (const float*)d_in[8];
  const float* b2f  = (const float*)d_in[9];
  const int* edge_src = (const int*)d_in[10];
  float* out = (float*)d_out;

  char* ws = (char*)d_ws;
  float* c1            = (float*)ws;                       // @0, 1 KiB
  unsigned short* W1f  = (unsigned short*)(ws + 4096);     // 128 KiB
  unsigned short* W2f  = (unsigned short*)(ws + 4096 + 131072);
  unsigned short* Yp   = (unsigned short*)(ws + 1048576);  // 48 MiB bf16 Y'
  const size_t need = 1048576 + (size_t)NSROWS * 256 * 2;

  hipLaunchKernelGGL(prep_c1, dim3(1), dim3(256), 0, stream, w1e, b1e, w2e, b2e, w1f, b1f, c1);
  hipLaunchKernelGGL(prep_w, dim3(32), dim3(256), 0, stream, w1f, w2f, W1f, W2f);
  if (ws_size >= need) {
    hipLaunchKernelGGL(k1_senders, dim3(NSROWS / 64), dim3(256), 0, stream, x, c1, W1f, Yp);
    hipLaunchKernelGGL(k23_recv, dim3(NRROWS / 64), dim3(256), 0, stream,
                       Yp, edge_src, W2f, b2f, out);
  } else {
    hipLaunchKernelGGL(heal_fused, dim3(NRROWS / 64), dim3(256), 0, stream,
                       x, edge_src, c1, W1f, W2f, b2f, out);
  }
}